// Round 27
// baseline (351.753 us; speedup 1.0000x reference)
//
#include <hip/hip_runtime.h>

#define NN 50000
#define EE 800000
#define TT 12
#define BB 2

// ws layout (4B units):
//  [0, 50048)            dinv
//  [50048, 2450048)      AX[b][n][t][f]  (BB*NN*TT*2 floats)
//  [2450048, 2454144)    P folded params (3*1120 + 12)
//  [2454144, 2504192)    cnt (int)
//  [2504192, 2554240)    off (int)
//  [2554240, 2604288)    cur (int)
//  [2604288, 2604416)    bsum (int)
//  [2604416, 2654464)    deg (float)
// CSR payload lives in d_out (fully overwritten by k_recur at the end):
//  d_out[0..1600000) as int2 epack[800000] = {src, float_bits(w)}
#define OFF_AX   50048
#define OFF_P    2450048
#define OFF_CNT  2454144
#define OFF_OFF  2504192
#define OFF_CUR  2554240
#define OFF_BSUM 2604288
#define OFF_DEG  2604416
#define NB_SCAN  98  // ceil(50000/512)
#define NNODES   (BB * NN)
#define NW       4
#define NBLK_REC 12500  // 50000 waves, 1 pair/wave, dual-node ILP (R26: 175us)

__device__ __forceinline__ float fsig(float x) {
    x = fminf(fmaxf(x, -30.f), 30.f);
    return __builtin_amdgcn_rcpf(1.f + __expf(-x));
}
__device__ __forceinline__ float ftanh(float x) {
    x = fminf(fmaxf(x, -15.f), 15.f);
    float e = __expf(-2.f * x);
    return (1.f - e) * __builtin_amdgcn_rcpf(1.f + e);
}

// count in-degree AND accumulate weighted degree in one edge pass
__global__ void k_count(const int* __restrict__ idx, const float* __restrict__ w,
                        int* __restrict__ cnt, float* __restrict__ deg) {
    int e = blockIdx.x * 256 + threadIdx.x;
    if (e < EE) {
        int c = idx[EE + e];
        atomicAdd(&cnt[c], 1);
        unsafeAtomicAdd(&deg[c], w[e]);
    }
}

// exclusive scan of cnt -> off (per-block), block totals -> bsum
__global__ void k_scanA(const int* __restrict__ cnt, int* __restrict__ off,
                        int* __restrict__ bsum) {
    __shared__ int sm[512];
    int i = blockIdx.x * 512 + threadIdx.x;
    int v = (i < NN) ? cnt[i] : 0;
    sm[threadIdx.x] = v;
    __syncthreads();
#pragma unroll
    for (int d = 1; d < 512; d <<= 1) {
        int t = (threadIdx.x >= d) ? sm[threadIdx.x - d] : 0;
        __syncthreads();
        sm[threadIdx.x] += t;
        __syncthreads();
    }
    if (i < NN) off[i] = sm[threadIdx.x] - v;  // exclusive within block
    if (threadIdx.x == 511) bsum[blockIdx.x] = sm[511];
}

__global__ void k_scanB(int* __restrict__ bsum) {
    __shared__ int sm[128];
    int tid = threadIdx.x;
    int v = (tid < NB_SCAN) ? bsum[tid] : 0;
    sm[tid] = v;
    __syncthreads();
#pragma unroll
    for (int d = 1; d < 128; d <<= 1) {
        int t = (tid >= d) ? sm[tid - d] : 0;
        __syncthreads();
        sm[tid] += t;
        __syncthreads();
    }
    if (tid < NB_SCAN) bsum[tid] = sm[tid] - v;  // exclusive
}

// finalize offsets + cur; also dinv = rsqrt(1 + deg) (folded k_degdinv)
__global__ void k_scanC(int* __restrict__ off, const int* __restrict__ bsum,
                        int* __restrict__ cur, const float* __restrict__ deg,
                        float* __restrict__ dinv) {
    int i = blockIdx.x * 256 + threadIdx.x;
    if (i < NN) {
        int o = off[i] + bsum[i >> 9];
        off[i] = o;
        cur[i] = o;
        dinv[i] = rsqrtf(1.f + deg[i]);
    }
}

// packed CSR fill: one 8B store per edge {src, float_bits(w)}
__global__ void k_fill(const int* __restrict__ idx, const float* __restrict__ w,
                       int* __restrict__ cur, int2* __restrict__ epack) {
    int e = blockIdx.x * 256 + threadIdx.x;
    if (e >= EE) return;
    int c = idx[EE + e];
    int s = atomicAdd(&cur[c], 1);
    epack[s] = make_int2(idx[e], __float_as_int(w[e]));
}

// AX[b][n][t][f] = dinv[n]^2 * X[b][n][f][t] + sum_in nrm * X[b][src][f][t]
__global__ __launch_bounds__(64) void k_gather(const float* __restrict__ X,
                                               const float* __restrict__ dinv,
                                               const int2* __restrict__ epack,
                                               const int* __restrict__ off,
                                               const int* __restrict__ cnt,
                                               float* __restrict__ AX) {
    int tid = blockIdx.x * 64 + threadIdx.x;  // b*NN + n
    if (tid >= NNODES) return;
    int b = tid / NN;
    int n = tid - b * NN;
    float di = dinv[n];
    const float* Xb = X + (size_t)b * NN * 24;

    float xf[24], acc[24];
    {
        const float4* xs = (const float4*)(Xb + (size_t)n * 24);
        float s = di * di;
#pragma unroll
        for (int q = 0; q < 6; q++) {
            float4 v = xs[q];
            xf[4 * q] = v.x; xf[4 * q + 1] = v.y; xf[4 * q + 2] = v.z; xf[4 * q + 3] = v.w;
        }
#pragma unroll
        for (int t = 0; t < TT; t++) {
            acc[2 * t] = s * xf[t];
            acc[2 * t + 1] = s * xf[12 + t];
        }
    }
    int s0 = off[n], c = cnt[n];
    for (int q = 0; q < c; q++) {
        int2 ep = epack[s0 + q];
        int r = ep.x;
        float nrm = dinv[r] * __int_as_float(ep.y) * di;
        const float4* xr = (const float4*)(Xb + (size_t)r * 24);
#pragma unroll
        for (int p = 0; p < 6; p++) {
            float4 v = xr[p];
            xf[4 * p] = v.x; xf[4 * p + 1] = v.y; xf[4 * p + 2] = v.z; xf[4 * p + 3] = v.w;
        }
#pragma unroll
        for (int t = 0; t < TT; t++) {
            acc[2 * t] = fmaf(nrm, xf[t], acc[2 * t]);
            acc[2 * t + 1] = fmaf(nrm, xf[12 + t], acc[2 * t + 1]);
        }
    }
    float4* o = (float4*)(AX + (size_t)tid * 24);
#pragma unroll
    for (int q = 0; q < 6; q++)
        o[q] = make_float4(acc[4 * q], acc[4 * q + 1], acc[4 * q + 2], acc[4 * q + 3]);
}

// fold weights: per gate g at base g*1120: WF0[j]=sum_k W[0][k]Lw[k][j], WF1, cF, LB[k][j]=Lw[32+k][j]
__global__ void k_fold(const float* __restrict__ Wz, const float* __restrict__ bz,
                       const float* __restrict__ Lwz, const float* __restrict__ Lbz,
                       const float* __restrict__ Wr, const float* __restrict__ br,
                       const float* __restrict__ Lwr, const float* __restrict__ Lbr,
                       const float* __restrict__ Wh, const float* __restrict__ bh,
                       const float* __restrict__ Lwh, const float* __restrict__ Lbh,
                       const float* __restrict__ att, float* __restrict__ P) {
    int tid = threadIdx.x;
    if (tid < 96) {
        int g = tid >> 5, j = tid & 31;
        const float* W  = g == 0 ? Wz  : (g == 1 ? Wr  : Wh);
        const float* b  = g == 0 ? bz  : (g == 1 ? br  : bh);
        const float* Lw = g == 0 ? Lwz : (g == 1 ? Lwr : Lwh);
        const float* Lb = g == 0 ? Lbz : (g == 1 ? Lbr : Lbh);
        float* out = P + g * 1120;
        float w0 = 0.f, w1 = 0.f, c = 0.f;
        for (int k = 0; k < 32; k++) {
            float lw = Lw[k * 32 + j];
            w0 += W[k] * lw;
            w1 += W[32 + k] * lw;
            c  += b[k] * lw;
        }
        out[j] = w0;
        out[32 + j] = w1;
        out[64 + j] = c + Lb[j];
        for (int k = 0; k < 32; k++) out[96 + k * 32 + j] = Lw[(32 + k) * 32 + j];
    } else if (tid == 96) {
        float m = -1e30f;
        for (int t = 0; t < TT; t++) m = fmaxf(m, att[t]);
        float s = 0.f;
        float e[TT];
        for (int t = 0; t < TT; t++) { e[t] = __expf(att[t] - m); s += e[t]; }
        for (int t = 0; t < TT; t++) P[3360 + t] = e[t] / s;
    }
}

// Dual-node k-split recurrence (R26, 175us): wave owns node pair, A/B computed
// concurrently (ILP); lane=(h,j) holds 16-k weight strip per gate.
__global__ __launch_bounds__(256, 2) void k_recur(const float* __restrict__ AX,
                                                  const float* __restrict__ P,
                                                  float* __restrict__ out) {
    __shared__ __align__(16) float Hs[NW][2][32];
    __shared__ __align__(16) float rHs[NW][2][32];
    __shared__ __align__(16) float AXs[NW][48];
    const int lane = threadIdx.x & 63;
    const int w = threadIdx.x >> 6;
    const int j = lane & 31;
    const int h = lane >> 5;
    const int k0 = h * 16;
    const int pair = blockIdx.x * NW + w;
    if (pair >= NNODES / 2) return;

    float LBz[16], LBr[16], LBh[16];
    float wz0 = P[j],        wz1 = P[32 + j],        cz = P[64 + j];
    float wr0 = P[1120 + j], wr1 = P[1120 + 32 + j], cr = P[1120 + 64 + j];
    float wh0 = P[2240 + j], wh1 = P[2240 + 32 + j], ch = P[2240 + 64 + j];
#pragma unroll
    for (int k = 0; k < 16; k++) {
        LBz[k] = P[96 + (k0 + k) * 32 + j];
        LBr[k] = P[1120 + 96 + (k0 + k) * 32 + j];
        LBh[k] = P[2240 + 96 + (k0 + k) * 32 + j];
    }

    if (lane < 48) AXs[w][lane] = AX[(size_t)pair * 48 + lane];

    // t = 0: H == 0 -> z/h init-only, rH == 0.
    float2 aA = *(const float2*)&AXs[w][0];
    float2 aB = *(const float2*)&AXs[w][24];
    float zA = fsig(fmaf(aA.x, wz0, fmaf(aA.y, wz1, cz)));
    float zB = fsig(fmaf(aB.x, wz0, fmaf(aB.y, wz1, cz)));
    float thA = ftanh(fmaf(aA.x, wh0, fmaf(aA.y, wh1, ch)));
    float thB = ftanh(fmaf(aB.x, wh0, fmaf(aB.y, wh1, ch)));
    float HA = (1.f - zA) * thA;
    float HB = (1.f - zB) * thB;
    float p0 = P[3360];
    float accA = p0 * HA, accB = p0 * HB;
    if (lane < 32) { Hs[w][0][j] = HA; Hs[w][1][j] = HB; }

#pragma unroll 1
    for (int t = 1; t < TT; t++) {
        aA = *(const float2*)&AXs[w][2 * t];
        aB = *(const float2*)&AXs[w][24 + 2 * t];
        float hbA[16], hbB[16];
#pragma unroll
        for (int i = 0; i < 4; i++) {
            float4 vA = *(const float4*)&Hs[w][0][k0 + 4 * i];
            float4 vB = *(const float4*)&Hs[w][1][k0 + 4 * i];
            hbA[4 * i] = vA.x; hbA[4 * i + 1] = vA.y; hbA[4 * i + 2] = vA.z; hbA[4 * i + 3] = vA.w;
            hbB[4 * i] = vB.x; hbB[4 * i + 1] = vB.y; hbB[4 * i + 2] = vB.z; hbB[4 * i + 3] = vB.w;
        }
        float srA, srB;
        {
            float a0 = 0.f, a1 = 0.f, b0 = 0.f, b1 = 0.f;
#pragma unroll
            for (int k = 0; k < 16; k += 2) {
                a0 = fmaf(hbA[k],     LBr[k],     a0);
                b0 = fmaf(hbB[k],     LBr[k],     b0);
                a1 = fmaf(hbA[k + 1], LBr[k + 1], a1);
                b1 = fmaf(hbB[k + 1], LBr[k + 1], b1);
            }
            srA = a0 + a1; srB = b0 + b1;
        }
        srA += __shfl_xor(srA, 32, 64);
        srB += __shfl_xor(srB, 32, 64);
        float rHA = fsig(fmaf(aA.x, wr0, fmaf(aA.y, wr1, cr)) + srA) * HA;
        float rHB = fsig(fmaf(aB.x, wr0, fmaf(aB.y, wr1, cr)) + srB) * HB;
        if (lane < 32) { rHs[w][0][j] = rHA; rHs[w][1][j] = rHB; }
        float szA, szB;
        {
            float a0 = 0.f, a1 = 0.f, b0 = 0.f, b1 = 0.f;
#pragma unroll
            for (int k = 0; k < 16; k += 2) {
                a0 = fmaf(hbA[k],     LBz[k],     a0);
                b0 = fmaf(hbB[k],     LBz[k],     b0);
                a1 = fmaf(hbA[k + 1], LBz[k + 1], a1);
                b1 = fmaf(hbB[k + 1], LBz[k + 1], b1);
            }
            szA = a0 + a1; szB = b0 + b1;
        }
        szA += __shfl_xor(szA, 32, 64);
        szB += __shfl_xor(szB, 32, 64);
        zA = fsig(fmaf(aA.x, wz0, fmaf(aA.y, wz1, cz)) + szA);
        zB = fsig(fmaf(aB.x, wz0, fmaf(aB.y, wz1, cz)) + szB);
        float shA, shB;
        {
            float a0 = 0.f, a1 = 0.f, b0 = 0.f, b1 = 0.f;
#pragma unroll
            for (int i = 0; i < 4; i++) {
                float4 vA = *(const float4*)&rHs[w][0][k0 + 4 * i];
                float4 vB = *(const float4*)&rHs[w][1][k0 + 4 * i];
                a0 = fmaf(vA.x, LBh[4 * i],     a0);
                b0 = fmaf(vB.x, LBh[4 * i],     b0);
                a1 = fmaf(vA.y, LBh[4 * i + 1], a1);
                b1 = fmaf(vB.y, LBh[4 * i + 1], b1);
                a0 = fmaf(vA.z, LBh[4 * i + 2], a0);
                b0 = fmaf(vB.z, LBh[4 * i + 2], b0);
                a1 = fmaf(vA.w, LBh[4 * i + 3], a1);
                b1 = fmaf(vB.w, LBh[4 * i + 3], b1);
            }
            shA = a0 + a1; shB = b0 + b1;
        }
        shA += __shfl_xor(shA, 32, 64);
        shB += __shfl_xor(shB, 32, 64);
        thA = ftanh(fmaf(aA.x, wh0, fmaf(aA.y, wh1, ch)) + shA);
        thB = ftanh(fmaf(aB.x, wh0, fmaf(aB.y, wh1, ch)) + shB);
        float HnA = fmaf(zA, HA - thA, thA);
        float HnB = fmaf(zB, HB - thB, thB);
        HA = HnA; HB = HnB;
        float pt = P[3360 + t];
        accA = fmaf(pt, HnA, accA);
        accB = fmaf(pt, HnB, accB);
        if (lane < 32 && t < TT - 1) { Hs[w][0][j] = HnA; Hs[w][1][j] = HnB; }
    }
    if (lane < 32) {
        out[(size_t)pair * 64 + j] = accA;
        out[(size_t)pair * 64 + 32 + j] = accB;
    }
}

extern "C" void kernel_launch(void* const* d_in, const int* in_sizes, int n_in,
                              void* d_out, int out_size, void* d_ws, size_t ws_size,
                              hipStream_t stream) {
    const float* X   = (const float*)d_in[0];
    const int*   idx = (const int*)d_in[1];
    const float* ew  = (const float*)d_in[2];
    const float* Wz  = (const float*)d_in[3];
    const float* bz  = (const float*)d_in[4];
    const float* Wr  = (const float*)d_in[5];
    const float* br  = (const float*)d_in[6];
    const float* Wh  = (const float*)d_in[7];
    const float* bh  = (const float*)d_in[8];
    const float* Lwz = (const float*)d_in[9];
    const float* Lbz = (const float*)d_in[10];
    const float* Lwr = (const float*)d_in[11];
    const float* Lbr = (const float*)d_in[12];
    const float* Lwh = (const float*)d_in[13];
    const float* Lbh = (const float*)d_in[14];
    const float* att = (const float*)d_in[15];

    float* ws   = (float*)d_ws;
    float* dinv = ws;
    float* AX   = ws + OFF_AX;
    float* P    = ws + OFF_P;
    int*   cnt  = (int*)ws + OFF_CNT;
    int*   off  = (int*)ws + OFF_OFF;
    int*   cur  = (int*)ws + OFF_CUR;
    int*   bsum = (int*)ws + OFF_BSUM;
    float* deg  = ws + OFF_DEG;
    float* out  = (float*)d_out;
    int2*  epack = (int2*)d_out;            // packed CSR scratch inside d_out

    hipMemsetAsync(cnt, 0, NN * sizeof(int), stream);
    hipMemsetAsync(deg, 0, NN * sizeof(float), stream);
    hipLaunchKernelGGL(k_count, dim3((EE + 255) / 256), dim3(256), 0, stream, idx, ew, cnt, deg);
    hipLaunchKernelGGL(k_scanA, dim3(NB_SCAN), dim3(512), 0, stream, cnt, off, bsum);
    hipLaunchKernelGGL(k_scanB, dim3(1), dim3(128), 0, stream, bsum);
    hipLaunchKernelGGL(k_scanC, dim3((NN + 255) / 256), dim3(256), 0, stream, off, bsum, cur, deg, dinv);
    hipLaunchKernelGGL(k_fill, dim3((EE + 255) / 256), dim3(256), 0, stream, idx, ew, cur, epack);
    hipLaunchKernelGGL(k_gather, dim3((NNODES + 63) / 64), dim3(64), 0, stream,
                       X, dinv, epack, off, cnt, AX);
    hipLaunchKernelGGL(k_fold, dim3(1), dim3(128), 0, stream,
                       Wz, bz, Lwz, Lbz, Wr, br, Lwr, Lbr, Wh, bh, Lwh, Lbh, att, P);
    hipLaunchKernelGGL(k_recur, dim3(NBLK_REC), dim3(256), 0, stream, AX, P, out);
}

// Round 28
// 315.107 us; speedup vs baseline: 1.1163x; 1.1163x over previous
//
#include <hip/hip_runtime.h>

#define NN 50000
#define EE 800000
#define TT 12
#define BB 2

// ws layout (4B units):
//  [0, 50048)            dinv
//  [50048, 2450048)      AX[b][n][t][f]  (BB*NN*TT*2 floats)
//  [2450048, 2454144)    P folded params (3*1120 + 12)
//  [2454144, 2504192)    cnt (int)
//  [2504192, 2554240)    off (int)
//  [2554240, 2604288)    cur (int)
//  [2604288, 2604416)    bsum (int)
// CSR payload lives in d_out (fully overwritten by k_recur at the end):
//  d_out[0..1600000) as int2 epack[800000] = {src, float_bits(w)}
#define OFF_AX   50048
#define OFF_P    2450048
#define OFF_CNT  2454144
#define OFF_OFF  2504192
#define OFF_CUR  2554240
#define OFF_BSUM 2604288
#define NB_SCAN  98  // ceil(50000/512)
#define NNODES   (BB * NN)
#define NW       4
#define NBLK_REC 12500  // 50000 waves, 1 pair/wave, dual-node ILP (R26: 175us)

__device__ __forceinline__ float fsig(float x) {
    x = fminf(fmaxf(x, -30.f), 30.f);
    return __builtin_amdgcn_rcpf(1.f + __expf(-x));
}
__device__ __forceinline__ float ftanh(float x) {
    x = fminf(fmaxf(x, -15.f), 15.f);
    float e = __expf(-2.f * x);
    return (1.f - e) * __builtin_amdgcn_rcpf(1.f + e);
}

__global__ void k_count(const int* __restrict__ idx, int* __restrict__ cnt) {
    int e = blockIdx.x * 256 + threadIdx.x;
    if (e < EE) atomicAdd(&cnt[idx[EE + e]], 1);
}

// exclusive scan of cnt -> off (per-block), block totals -> bsum
__global__ void k_scanA(const int* __restrict__ cnt, int* __restrict__ off,
                        int* __restrict__ bsum) {
    __shared__ int sm[512];
    int i = blockIdx.x * 512 + threadIdx.x;
    int v = (i < NN) ? cnt[i] : 0;
    sm[threadIdx.x] = v;
    __syncthreads();
#pragma unroll
    for (int d = 1; d < 512; d <<= 1) {
        int t = (threadIdx.x >= d) ? sm[threadIdx.x - d] : 0;
        __syncthreads();
        sm[threadIdx.x] += t;
        __syncthreads();
    }
    if (i < NN) off[i] = sm[threadIdx.x] - v;  // exclusive within block
    if (threadIdx.x == 511) bsum[blockIdx.x] = sm[511];
}

__global__ void k_scanB(int* __restrict__ bsum) {
    __shared__ int sm[128];
    int tid = threadIdx.x;
    int v = (tid < NB_SCAN) ? bsum[tid] : 0;
    sm[tid] = v;
    __syncthreads();
#pragma unroll
    for (int d = 1; d < 128; d <<= 1) {
        int t = (tid >= d) ? sm[tid - d] : 0;
        __syncthreads();
        sm[tid] += t;
        __syncthreads();
    }
    if (tid < NB_SCAN) bsum[tid] = sm[tid] - v;  // exclusive
}

__global__ void k_scanC(int* __restrict__ off, const int* __restrict__ bsum,
                        int* __restrict__ cur) {
    int i = blockIdx.x * 256 + threadIdx.x;
    if (i < NN) {
        int o = off[i] + bsum[i >> 9];
        off[i] = o;
        cur[i] = o;
    }
}

// packed CSR fill: one 8B store per edge {src, float_bits(w)}
__global__ void k_fill(const int* __restrict__ idx, const float* __restrict__ w,
                       int* __restrict__ cur, int2* __restrict__ epack) {
    int e = blockIdx.x * 256 + threadIdx.x;
    if (e >= EE) return;
    int c = idx[EE + e];
    int s = atomicAdd(&cur[c], 1);
    epack[s] = make_int2(idx[e], __float_as_int(w[e]));
}

__global__ void k_degdinv(const int* __restrict__ off, const int* __restrict__ cnt,
                          const int2* __restrict__ epack, float* __restrict__ dinv) {
    int n = blockIdx.x * 256 + threadIdx.x;
    if (n >= NN) return;
    int s0 = off[n], c = cnt[n];
    float d = 1.f;  // self loop
    for (int q = 0; q < c; q++) d += __int_as_float(epack[s0 + q].y);
    dinv[n] = rsqrtf(d);
}

// AX[b][n][t][f] = dinv[n]^2 * X[b][n][f][t] + sum_in nrm * X[b][src][f][t]
__global__ __launch_bounds__(64) void k_gather(const float* __restrict__ X,
                                               const float* __restrict__ dinv,
                                               const int2* __restrict__ epack,
                                               const int* __restrict__ off,
                                               const int* __restrict__ cnt,
                                               float* __restrict__ AX) {
    int tid = blockIdx.x * 64 + threadIdx.x;  // b*NN + n
    if (tid >= NNODES) return;
    int b = tid / NN;
    int n = tid - b * NN;
    float di = dinv[n];
    const float* Xb = X + (size_t)b * NN * 24;

    float xf[24], acc[24];
    {
        const float4* xs = (const float4*)(Xb + (size_t)n * 24);
        float s = di * di;
#pragma unroll
        for (int q = 0; q < 6; q++) {
            float4 v = xs[q];
            xf[4 * q] = v.x; xf[4 * q + 1] = v.y; xf[4 * q + 2] = v.z; xf[4 * q + 3] = v.w;
        }
#pragma unroll
        for (int t = 0; t < TT; t++) {
            acc[2 * t] = s * xf[t];
            acc[2 * t + 1] = s * xf[12 + t];
        }
    }
    int s0 = off[n], c = cnt[n];
    for (int q = 0; q < c; q++) {
        int2 ep = epack[s0 + q];
        int r = ep.x;
        float nrm = dinv[r] * __int_as_float(ep.y) * di;
        const float4* xr = (const float4*)(Xb + (size_t)r * 24);
#pragma unroll
        for (int p = 0; p < 6; p++) {
            float4 v = xr[p];
            xf[4 * p] = v.x; xf[4 * p + 1] = v.y; xf[4 * p + 2] = v.z; xf[4 * p + 3] = v.w;
        }
#pragma unroll
        for (int t = 0; t < TT; t++) {
            acc[2 * t] = fmaf(nrm, xf[t], acc[2 * t]);
            acc[2 * t + 1] = fmaf(nrm, xf[12 + t], acc[2 * t + 1]);
        }
    }
    float4* o = (float4*)(AX + (size_t)tid * 24);
#pragma unroll
    for (int q = 0; q < 6; q++)
        o[q] = make_float4(acc[4 * q], acc[4 * q + 1], acc[4 * q + 2], acc[4 * q + 3]);
}

// fold weights: per gate g at base g*1120: WF0[j]=sum_k W[0][k]Lw[k][j], WF1, cF, LB[k][j]=Lw[32+k][j]
__global__ void k_fold(const float* __restrict__ Wz, const float* __restrict__ bz,
                       const float* __restrict__ Lwz, const float* __restrict__ Lbz,
                       const float* __restrict__ Wr, const float* __restrict__ br,
                       const float* __restrict__ Lwr, const float* __restrict__ Lbr,
                       const float* __restrict__ Wh, const float* __restrict__ bh,
                       const float* __restrict__ Lwh, const float* __restrict__ Lbh,
                       const float* __restrict__ att, float* __restrict__ P) {
    int tid = threadIdx.x;
    if (tid < 96) {
        int g = tid >> 5, j = tid & 31;
        const float* W  = g == 0 ? Wz  : (g == 1 ? Wr  : Wh);
        const float* b  = g == 0 ? bz  : (g == 1 ? br  : bh);
        const float* Lw = g == 0 ? Lwz : (g == 1 ? Lwr : Lwh);
        const float* Lb = g == 0 ? Lbz : (g == 1 ? Lbr : Lbh);
        float* out = P + g * 1120;
        float w0 = 0.f, w1 = 0.f, c = 0.f;
        for (int k = 0; k < 32; k++) {
            float lw = Lw[k * 32 + j];
            w0 += W[k] * lw;
            w1 += W[32 + k] * lw;
            c  += b[k] * lw;
        }
        out[j] = w0;
        out[32 + j] = w1;
        out[64 + j] = c + Lb[j];
        for (int k = 0; k < 32; k++) out[96 + k * 32 + j] = Lw[(32 + k) * 32 + j];
    } else if (tid == 96) {
        float m = -1e30f;
        for (int t = 0; t < TT; t++) m = fmaxf(m, att[t]);
        float s = 0.f;
        float e[TT];
        for (int t = 0; t < TT; t++) { e[t] = __expf(att[t] - m); s += e[t]; }
        for (int t = 0; t < TT; t++) P[3360 + t] = e[t] / s;
    }
}

// Dual-node k-split recurrence (R26, 175us): wave owns node pair, A/B computed
// concurrently (ILP); lane=(h,j) holds 16-k weight strip per gate.
__global__ __launch_bounds__(256, 2) void k_recur(const float* __restrict__ AX,
                                                  const float* __restrict__ P,
                                                  float* __restrict__ out) {
    __shared__ __align__(16) float Hs[NW][2][32];
    __shared__ __align__(16) float rHs[NW][2][32];
    __shared__ __align__(16) float AXs[NW][48];
    const int lane = threadIdx.x & 63;
    const int w = threadIdx.x >> 6;
    const int j = lane & 31;
    const int h = lane >> 5;
    const int k0 = h * 16;
    const int pair = blockIdx.x * NW + w;
    if (pair >= NNODES / 2) return;

    float LBz[16], LBr[16], LBh[16];
    float wz0 = P[j],        wz1 = P[32 + j],        cz = P[64 + j];
    float wr0 = P[1120 + j], wr1 = P[1120 + 32 + j], cr = P[1120 + 64 + j];
    float wh0 = P[2240 + j], wh1 = P[2240 + 32 + j], ch = P[2240 + 64 + j];
#pragma unroll
    for (int k = 0; k < 16; k++) {
        LBz[k] = P[96 + (k0 + k) * 32 + j];
        LBr[k] = P[1120 + 96 + (k0 + k) * 32 + j];
        LBh[k] = P[2240 + 96 + (k0 + k) * 32 + j];
    }

    if (lane < 48) AXs[w][lane] = AX[(size_t)pair * 48 + lane];

    // t = 0: H == 0 -> z/h init-only, rH == 0.
    float2 aA = *(const float2*)&AXs[w][0];
    float2 aB = *(const float2*)&AXs[w][24];
    float zA = fsig(fmaf(aA.x, wz0, fmaf(aA.y, wz1, cz)));
    float zB = fsig(fmaf(aB.x, wz0, fmaf(aB.y, wz1, cz)));
    float thA = ftanh(fmaf(aA.x, wh0, fmaf(aA.y, wh1, ch)));
    float thB = ftanh(fmaf(aB.x, wh0, fmaf(aB.y, wh1, ch)));
    float HA = (1.f - zA) * thA;
    float HB = (1.f - zB) * thB;
    float p0 = P[3360];
    float accA = p0 * HA, accB = p0 * HB;
    if (lane < 32) { Hs[w][0][j] = HA; Hs[w][1][j] = HB; }

#pragma unroll 1
    for (int t = 1; t < TT; t++) {
        aA = *(const float2*)&AXs[w][2 * t];
        aB = *(const float2*)&AXs[w][24 + 2 * t];
        float hbA[16], hbB[16];
#pragma unroll
        for (int i = 0; i < 4; i++) {
            float4 vA = *(const float4*)&Hs[w][0][k0 + 4 * i];
            float4 vB = *(const float4*)&Hs[w][1][k0 + 4 * i];
            hbA[4 * i] = vA.x; hbA[4 * i + 1] = vA.y; hbA[4 * i + 2] = vA.z; hbA[4 * i + 3] = vA.w;
            hbB[4 * i] = vB.x; hbB[4 * i + 1] = vB.y; hbB[4 * i + 2] = vB.z; hbB[4 * i + 3] = vB.w;
        }
        float srA, srB;
        {
            float a0 = 0.f, a1 = 0.f, b0 = 0.f, b1 = 0.f;
#pragma unroll
            for (int k = 0; k < 16; k += 2) {
                a0 = fmaf(hbA[k],     LBr[k],     a0);
                b0 = fmaf(hbB[k],     LBr[k],     b0);
                a1 = fmaf(hbA[k + 1], LBr[k + 1], a1);
                b1 = fmaf(hbB[k + 1], LBr[k + 1], b1);
            }
            srA = a0 + a1; srB = b0 + b1;
        }
        srA += __shfl_xor(srA, 32, 64);
        srB += __shfl_xor(srB, 32, 64);
        float rHA = fsig(fmaf(aA.x, wr0, fmaf(aA.y, wr1, cr)) + srA) * HA;
        float rHB = fsig(fmaf(aB.x, wr0, fmaf(aB.y, wr1, cr)) + srB) * HB;
        if (lane < 32) { rHs[w][0][j] = rHA; rHs[w][1][j] = rHB; }
        float szA, szB;
        {
            float a0 = 0.f, a1 = 0.f, b0 = 0.f, b1 = 0.f;
#pragma unroll
            for (int k = 0; k < 16; k += 2) {
                a0 = fmaf(hbA[k],     LBz[k],     a0);
                b0 = fmaf(hbB[k],     LBz[k],     b0);
                a1 = fmaf(hbA[k + 1], LBz[k + 1], a1);
                b1 = fmaf(hbB[k + 1], LBz[k + 1], b1);
            }
            szA = a0 + a1; szB = b0 + b1;
        }
        szA += __shfl_xor(szA, 32, 64);
        szB += __shfl_xor(szB, 32, 64);
        zA = fsig(fmaf(aA.x, wz0, fmaf(aA.y, wz1, cz)) + szA);
        zB = fsig(fmaf(aB.x, wz0, fmaf(aB.y, wz1, cz)) + szB);
        float shA, shB;
        {
            float a0 = 0.f, a1 = 0.f, b0 = 0.f, b1 = 0.f;
#pragma unroll
            for (int i = 0; i < 4; i++) {
                float4 vA = *(const float4*)&rHs[w][0][k0 + 4 * i];
                float4 vB = *(const float4*)&rHs[w][1][k0 + 4 * i];
                a0 = fmaf(vA.x, LBh[4 * i],     a0);
                b0 = fmaf(vB.x, LBh[4 * i],     b0);
                a1 = fmaf(vA.y, LBh[4 * i + 1], a1);
                b1 = fmaf(vB.y, LBh[4 * i + 1], b1);
                a0 = fmaf(vA.z, LBh[4 * i + 2], a0);
                b0 = fmaf(vB.z, LBh[4 * i + 2], b0);
                a1 = fmaf(vA.w, LBh[4 * i + 3], a1);
                b1 = fmaf(vB.w, LBh[4 * i + 3], b1);
            }
            shA = a0 + a1; shB = b0 + b1;
        }
        shA += __shfl_xor(shA, 32, 64);
        shB += __shfl_xor(shB, 32, 64);
        thA = ftanh(fmaf(aA.x, wh0, fmaf(aA.y, wh1, ch)) + shA);
        thB = ftanh(fmaf(aB.x, wh0, fmaf(aB.y, wh1, ch)) + shB);
        float HnA = fmaf(zA, HA - thA, thA);
        float HnB = fmaf(zB, HB - thB, thB);
        HA = HnA; HB = HnB;
        float pt = P[3360 + t];
        accA = fmaf(pt, HnA, accA);
        accB = fmaf(pt, HnB, accB);
        if (lane < 32 && t < TT - 1) { Hs[w][0][j] = HnA; Hs[w][1][j] = HnB; }
    }
    if (lane < 32) {
        out[(size_t)pair * 64 + j] = accA;
        out[(size_t)pair * 64 + 32 + j] = accB;
    }
}

extern "C" void kernel_launch(void* const* d_in, const int* in_sizes, int n_in,
                              void* d_out, int out_size, void* d_ws, size_t ws_size,
                              hipStream_t stream) {
    const float* X   = (const float*)d_in[0];
    const int*   idx = (const int*)d_in[1];
    const float* ew  = (const float*)d_in[2];
    const float* Wz  = (const float*)d_in[3];
    const float* bz  = (const float*)d_in[4];
    const float* Wr  = (const float*)d_in[5];
    const float* br  = (const float*)d_in[6];
    const float* Wh  = (const float*)d_in[7];
    const float* bh  = (const float*)d_in[8];
    const float* Lwz = (const float*)d_in[9];
    const float* Lbz = (const float*)d_in[10];
    const float* Lwr = (const float*)d_in[11];
    const float* Lbr = (const float*)d_in[12];
    const float* Lwh = (const float*)d_in[13];
    const float* Lbh = (const float*)d_in[14];
    const float* att = (const float*)d_in[15];

    float* ws   = (float*)d_ws;
    float* dinv = ws;
    float* AX   = ws + OFF_AX;
    float* P    = ws + OFF_P;
    int*   cnt  = (int*)ws + OFF_CNT;
    int*   off  = (int*)ws + OFF_OFF;
    int*   cur  = (int*)ws + OFF_CUR;
    int*   bsum = (int*)ws + OFF_BSUM;
    float* out  = (float*)d_out;
    int2*  epack = (int2*)d_out;            // packed CSR scratch inside d_out

    hipMemsetAsync(cnt, 0, NN * sizeof(int), stream);
    hipLaunchKernelGGL(k_count, dim3((EE + 255) / 256), dim3(256), 0, stream, idx, cnt);
    hipLaunchKernelGGL(k_scanA, dim3(NB_SCAN), dim3(512), 0, stream, cnt, off, bsum);
    hipLaunchKernelGGL(k_scanB, dim3(1), dim3(128), 0, stream, bsum);
    hipLaunchKernelGGL(k_scanC, dim3((NN + 255) / 256), dim3(256), 0, stream, off, bsum, cur);
    hipLaunchKernelGGL(k_fill, dim3((EE + 255) / 256), dim3(256), 0, stream, idx, ew, cur, epack);
    hipLaunchKernelGGL(k_degdinv, dim3((NN + 255) / 256), dim3(256), 0, stream, off, cnt, epack, dinv);
    hipLaunchKernelGGL(k_gather, dim3((NNODES + 63) / 64), dim3(64), 0, stream,
                       X, dinv, epack, off, cnt, AX);
    hipLaunchKernelGGL(k_fold, dim3(1), dim3(128), 0, stream,
                       Wz, bz, Lwz, Lbz, Wr, br, Lwr, Lbr, Wh, bh, Lwh, Lbh, att, P);
    hipLaunchKernelGGL(k_recur, dim3(NBLK_REC), dim3(256), 0, stream, AX, P, out);
}